// Round 1
// baseline (563.451 us; speedup 1.0000x reference)
//
#include <hip/hip_runtime.h>
#include <math.h>

#define NB 8192
#define NC 1024
#define NS 16

// ws layout (floats):
// [0] sum, [1] sumsq, [2] prob accumulator, [3] inv_s
// [8..23]  t_k
// [24..39] c_k = log_ndtr(t_k)

__device__ __forceinline__ float log_ndtr_f(float x) {
    // Phi(x) = 0.5 * erfc(-x/sqrt(2))
    float e = erfcf(-x * 0.70710678118654752f);
    if (e > 1e-37f) {
        return __logf(0.5f * e);
    }
    // asymptotic tail for very negative x (only hit when result underflows anyway)
    return -0.5f * x * x - 0.91893853320467274f - __logf(-x);
}

__global__ void k_init(float* ws) {
    int i = threadIdx.x;
    if (i < 8) ws[i] = 0.0f;
}

__global__ __launch_bounds__(256) void k_reduce(const float4* __restrict__ x, float* ws) {
    const int total = (NB * NC) / 4;
    int idx = blockIdx.x * blockDim.x + threadIdx.x;
    float s = 0.0f, ss = 0.0f;
    for (int i = idx; i < total; i += gridDim.x * blockDim.x) {
        float4 v = x[i];
        s  += v.x + v.y + v.z + v.w;
        ss += v.x * v.x + v.y * v.y + v.z * v.z + v.w * v.w;
    }
    #pragma unroll
    for (int m = 32; m; m >>= 1) {
        s  += __shfl_xor(s,  m, 64);
        ss += __shfl_xor(ss, m, 64);
    }
    __shared__ float ls[4], lss[4];
    int wid = threadIdx.x >> 6, lane = threadIdx.x & 63;
    if (lane == 0) { ls[wid] = s; lss[wid] = ss; }
    __syncthreads();
    if (threadIdx.x == 0) {
        float S1 = ls[0] + ls[1] + ls[2] + ls[3];
        float S2 = lss[0] + lss[1] + lss[2] + lss[3];
        atomicAdd(&ws[0], S1);
        atomicAdd(&ws[1], S2);
    }
}

__global__ void k_prep(const float* __restrict__ temp, float* ws) {
    if (threadIdx.x != 0 || blockIdx.x != 0) return;
    double sum = (double)ws[0];
    double sumsq = (double)ws[1];
    const double N = (double)NB * (double)NC;
    double var = (sumsq - sum * sum / N) / (N - 1.0);
    double stdv = sqrt(var);
    ws[3] = (float)(1.0 / (stdv * (double)temp[0]));
    for (int k = 0; k < NS; ++k) {
        double p = ((double)k + 0.5) / (double)NS;
        // Newton solve Phi(x) = p in double
        double xx = 0.0;
        for (int it = 0; it < 60; ++it) {
            double cdf = 0.5 * erfc(-xx * 0.70710678118654752440);
            double pdf = exp(-0.5 * xx * xx) * 0.39894228040143267794;
            double step = (cdf - p) / pdf;
            if (step > 2.0) step = 2.0;
            else if (step < -2.0) step = -2.0;
            xx -= step;
        }
        float tkf = (float)xx;
        ws[8 + k]  = tkf;
        ws[24 + k] = log_ndtr_f(tkf);
    }
}

__global__ __launch_bounds__(256) void k_main(const float* __restrict__ logits,
                                              const int* __restrict__ labels,
                                              const float* __restrict__ ws,
                                              float* __restrict__ acc) {
    const int b = blockIdx.x;
    const float inv_s = ws[3];
    float tk[NS], ck[NS];
    #pragma unroll
    for (int k = 0; k < NS; ++k) { tk[k] = ws[8 + k]; ck[k] = ws[24 + k]; }

    const float* row = logits + (size_t)b * NC;
    const float tgt = row[labels[b]];
    float4 v = reinterpret_cast<const float4*>(row)[threadIdx.x];
    float d[4];
    d[0] = (tgt - v.x) * inv_s;
    d[1] = (tgt - v.y) * inv_s;
    d[2] = (tgt - v.z) * inv_s;
    d[3] = (tgt - v.w) * inv_s;

    float a[NS];
    #pragma unroll
    for (int k = 0; k < NS; ++k) a[k] = 0.0f;

    #pragma unroll
    for (int j = 0; j < 4; ++j) {
        #pragma unroll
        for (int k = 0; k < NS; ++k) {
            a[k] += log_ndtr_f(d[j] + tk[k]);
        }
    }

    // wave reduce each of the 16 accumulators
    #pragma unroll
    for (int k = 0; k < NS; ++k) {
        #pragma unroll
        for (int m = 32; m; m >>= 1) a[k] += __shfl_xor(a[k], m, 64);
    }

    __shared__ float red[4][NS];
    int wid = threadIdx.x >> 6, lane = threadIdx.x & 63;
    if (lane == 0) {
        #pragma unroll
        for (int k = 0; k < NS; ++k) red[wid][k] = a[k];
    }
    __syncthreads();
    if (threadIdx.x < NS) {
        int k = threadIdx.x;
        float sk = red[0][k] + red[1][k] + red[2][k] + red[3][k];
        // logp_k = (sum over all j) - target term
        float p = __expf(sk - ck[k]);
        p += __shfl_xor(p, 8, 16);
        p += __shfl_xor(p, 4, 16);
        p += __shfl_xor(p, 2, 16);
        p += __shfl_xor(p, 1, 16);
        if (k == 0) atomicAdd(acc, p * (1.0f / (float)NS));
    }
}

__global__ void k_final(const float* __restrict__ ws, float* __restrict__ out) {
    if (threadIdx.x == 0 && blockIdx.x == 0) {
        out[0] = 1.0f - ws[2] * (1.0f / (float)NB);
    }
}

extern "C" void kernel_launch(void* const* d_in, const int* in_sizes, int n_in,
                              void* d_out, int out_size, void* d_ws, size_t ws_size,
                              hipStream_t stream) {
    const float* logits = (const float*)d_in[0];
    const int*   labels = (const int*)d_in[1];
    const float* temp   = (const float*)d_in[2];
    float* ws  = (float*)d_ws;
    float* out = (float*)d_out;

    hipLaunchKernelGGL(k_init,   dim3(1),    dim3(64),  0, stream, ws);
    hipLaunchKernelGGL(k_reduce, dim3(1024), dim3(256), 0, stream,
                       (const float4*)logits, ws);
    hipLaunchKernelGGL(k_prep,   dim3(1),    dim3(1),   0, stream, temp, ws);
    hipLaunchKernelGGL(k_main,   dim3(NB),   dim3(256), 0, stream,
                       logits, labels, ws, &ws[2]);
    hipLaunchKernelGGL(k_final,  dim3(1),    dim3(1),   0, stream, ws, out);
}

// Round 2
// 217.946 us; speedup vs baseline: 2.5853x; 2.5853x over previous
//
#include <hip/hip_runtime.h>
#include <math.h>

#define NB 8192
#define NC 1024
#define NS 16

// ws layout (floats):
// [0] sum, [1] sumsq, [2] prob accumulator, [3] inv_s
// [8..23]  t_k
// [24..39] c_k = log_ndtr(t_k)

__device__ __forceinline__ float log_ndtr_f(float x) {
    // Phi(x) = 0.5 * erfc(-x/sqrt(2))
    float e = erfcf(-x * 0.70710678118654752f);
    if (e > 1e-37f) {
        return __logf(0.5f * e);
    }
    // asymptotic tail for very negative x (only hit when result underflows anyway)
    return -0.5f * x * x - 0.91893853320467274f - __logf(-x);
}

__global__ void k_init(float* ws) {
    int i = threadIdx.x;
    if (i < 8) ws[i] = 0.0f;
}

__global__ __launch_bounds__(256) void k_reduce(const float4* __restrict__ x, float* ws) {
    const int total = (NB * NC) / 4;
    int idx = blockIdx.x * blockDim.x + threadIdx.x;
    float s = 0.0f, ss = 0.0f;
    for (int i = idx; i < total; i += gridDim.x * blockDim.x) {
        float4 v = x[i];
        s  += v.x + v.y + v.z + v.w;
        ss += v.x * v.x + v.y * v.y + v.z * v.z + v.w * v.w;
    }
    #pragma unroll
    for (int m = 32; m; m >>= 1) {
        s  += __shfl_xor(s,  m, 64);
        ss += __shfl_xor(ss, m, 64);
    }
    __shared__ float ls[4], lss[4];
    int wid = threadIdx.x >> 6, lane = threadIdx.x & 63;
    if (lane == 0) { ls[wid] = s; lss[wid] = ss; }
    __syncthreads();
    if (threadIdx.x == 0) {
        float S1 = ls[0] + ls[1] + ls[2] + ls[3];
        float S2 = lss[0] + lss[1] + lss[2] + lss[3];
        atomicAdd(&ws[0], S1);
        atomicAdd(&ws[1], S2);
    }
}

// Acklam's inverse normal CDF approximation (double), |rel err| < 1.2e-9,
// then Newton-refined to full double precision.
__device__ double ndtri_acklam(double p) {
    const double a0 = -3.969683028665376e+01, a1 = 2.209460984245205e+02,
                 a2 = -2.759285104469687e+02, a3 = 1.383577518672690e+02,
                 a4 = -3.066479806614716e+01, a5 = 2.506628277459239e+00;
    const double b0 = -5.447609879822406e+01, b1 = 1.615858368580409e+02,
                 b2 = -1.556989798598866e+02, b3 = 6.680131188771972e+01,
                 b4 = -1.328068155288572e+01;
    const double c0 = -7.784894002430293e-03, c1 = -3.223964580411365e-01,
                 c2 = -2.400758277161838e+00, c3 = -2.549732539343734e+00,
                 c4 =  4.374664141464968e+00, c5 =  2.938163982698783e+00;
    const double d0 = 7.784695709041462e-03, d1 = 3.224671290700398e-01,
                 d2 = 2.445134137142996e+00, d3 = 3.754408661907416e+00;
    const double plow = 0.02425;
    double x;
    if (p < plow) {
        double q = sqrt(-2.0 * log(p));
        x = (((((c0*q+c1)*q+c2)*q+c3)*q+c4)*q+c5) /
            ((((d0*q+d1)*q+d2)*q+d3)*q+1.0);
    } else if (p > 1.0 - plow) {
        double q = sqrt(-2.0 * log(1.0 - p));
        x = -(((((c0*q+c1)*q+c2)*q+c3)*q+c4)*q+c5) /
             ((((d0*q+d1)*q+d2)*q+d3)*q+1.0);
    } else {
        double q = p - 0.5, r = q * q;
        x = (((((a0*r+a1)*r+a2)*r+a3)*r+a4)*r+a5)*q /
            (((((b0*r+b1)*r+b2)*r+b3)*r+b4)*r+1.0);
    }
    // 3 Newton refinements in double
    #pragma unroll
    for (int it = 0; it < 3; ++it) {
        double cdf = 0.5 * erfc(-x * 0.70710678118654752440);
        double pdf = exp(-0.5 * x * x) * 0.39894228040143267794;
        x -= (cdf - p) / pdf;
    }
    return x;
}

__global__ void k_prep(const float* __restrict__ temp, float* ws) {
    int k = threadIdx.x;
    if (k == 0) {
        double sum = (double)ws[0];
        double sumsq = (double)ws[1];
        const double N = (double)NB * (double)NC;
        double var = (sumsq - sum * sum / N) / (N - 1.0);
        ws[3] = (float)(1.0 / (sqrt(var) * (double)temp[0]));
    }
    if (k < NS) {
        double p = ((double)k + 0.5) / (double)NS;
        float tkf = (float)ndtri_acklam(p);
        ws[8 + k]  = tkf;
        ws[24 + k] = log_ndtr_f(tkf);
    }
}

__global__ __launch_bounds__(256) void k_main(const float* __restrict__ logits,
                                              const int* __restrict__ labels,
                                              const float* __restrict__ ws,
                                              float* __restrict__ acc) {
    const int b = blockIdx.x;
    const float inv_s = ws[3];
    float tk[NS], ck[NS];
    #pragma unroll
    for (int k = 0; k < NS; ++k) { tk[k] = ws[8 + k]; ck[k] = ws[24 + k]; }

    const float* row = logits + (size_t)b * NC;
    const float tgt = row[labels[b]];
    float4 v = reinterpret_cast<const float4*>(row)[threadIdx.x];
    float d[4];
    d[0] = (tgt - v.x) * inv_s;
    d[1] = (tgt - v.y) * inv_s;
    d[2] = (tgt - v.z) * inv_s;
    d[3] = (tgt - v.w) * inv_s;

    float a[NS];
    #pragma unroll
    for (int k = 0; k < NS; ++k) a[k] = 0.0f;

    #pragma unroll
    for (int j = 0; j < 4; ++j) {
        #pragma unroll
        for (int k = 0; k < NS; ++k) {
            a[k] += log_ndtr_f(d[j] + tk[k]);
        }
    }

    // wave reduce each of the 16 accumulators
    #pragma unroll
    for (int k = 0; k < NS; ++k) {
        #pragma unroll
        for (int m = 32; m; m >>= 1) a[k] += __shfl_xor(a[k], m, 64);
    }

    __shared__ float red[4][NS];
    int wid = threadIdx.x >> 6, lane = threadIdx.x & 63;
    if (lane == 0) {
        #pragma unroll
        for (int k = 0; k < NS; ++k) red[wid][k] = a[k];
    }
    __syncthreads();
    if (threadIdx.x < NS) {
        int k = threadIdx.x;
        float sk = red[0][k] + red[1][k] + red[2][k] + red[3][k];
        // logp_k = (sum over all j) - target term
        float p = __expf(sk - ck[k]);
        p += __shfl_xor(p, 8, 16);
        p += __shfl_xor(p, 4, 16);
        p += __shfl_xor(p, 2, 16);
        p += __shfl_xor(p, 1, 16);
        if (k == 0) atomicAdd(acc, p * (1.0f / (float)NS));
    }
}

__global__ void k_final(const float* __restrict__ ws, float* __restrict__ out) {
    if (threadIdx.x == 0 && blockIdx.x == 0) {
        out[0] = 1.0f - ws[2] * (1.0f / (float)NB);
    }
}

extern "C" void kernel_launch(void* const* d_in, const int* in_sizes, int n_in,
                              void* d_out, int out_size, void* d_ws, size_t ws_size,
                              hipStream_t stream) {
    const float* logits = (const float*)d_in[0];
    const int*   labels = (const int*)d_in[1];
    const float* temp   = (const float*)d_in[2];
    float* ws  = (float*)d_ws;
    float* out = (float*)d_out;

    hipLaunchKernelGGL(k_init,   dim3(1),    dim3(64),  0, stream, ws);
    hipLaunchKernelGGL(k_reduce, dim3(1024), dim3(256), 0, stream,
                       (const float4*)logits, ws);
    hipLaunchKernelGGL(k_prep,   dim3(1),    dim3(64),  0, stream, temp, ws);
    hipLaunchKernelGGL(k_main,   dim3(NB),   dim3(256), 0, stream,
                       logits, labels, ws, &ws[2]);
    hipLaunchKernelGGL(k_final,  dim3(1),    dim3(1),   0, stream, ws, out);
}

// Round 3
// 110.674 us; speedup vs baseline: 5.0911x; 1.9693x over previous
//
#include <hip/hip_runtime.h>
#include <math.h>

#define NB 8192
#define NC 1024
#define NS 16
#define ROWS 4

// log_ndtr table: x in [XLO, XLO + (NT-1)*H], H = 1/64
#define NT 1217
#define XLO -13.0f
#define INVH 64.0f

// ws layout (floats):
// [0] sum, [1] sumsq, [2] prob accumulator, [3] inv_s
// [8..23]  t_k
// [24..39] c_k = log_ndtr(t_k) exact
// [64..]   table: NT float2 entries {v_i, v_{i+1}-v_i}

__device__ __forceinline__ float log_ndtr_f(float x) {
    float e = erfcf(-x * 0.70710678118654752f);
    if (e > 1e-37f) {
        return __logf(0.5f * e);
    }
    return -0.5f * x * x - 0.91893853320467274f - __logf(-x);
}

__global__ void k_init(float* ws) {
    int i = threadIdx.x;
    if (i < 8) ws[i] = 0.0f;
}

__global__ __launch_bounds__(256) void k_reduce(const float4* __restrict__ x, float* ws) {
    const int total = (NB * NC) / 4;
    int idx = blockIdx.x * blockDim.x + threadIdx.x;
    float s = 0.0f, ss = 0.0f;
    for (int i = idx; i < total; i += gridDim.x * blockDim.x) {
        float4 v = x[i];
        s  += v.x + v.y + v.z + v.w;
        ss += v.x * v.x + v.y * v.y + v.z * v.z + v.w * v.w;
    }
    #pragma unroll
    for (int m = 32; m; m >>= 1) {
        s  += __shfl_xor(s,  m, 64);
        ss += __shfl_xor(ss, m, 64);
    }
    __shared__ float ls[4], lss[4];
    int wid = threadIdx.x >> 6, lane = threadIdx.x & 63;
    if (lane == 0) { ls[wid] = s; lss[wid] = ss; }
    __syncthreads();
    if (threadIdx.x == 0) {
        atomicAdd(&ws[0], ls[0] + ls[1] + ls[2] + ls[3]);
        atomicAdd(&ws[1], lss[0] + lss[1] + lss[2] + lss[3]);
    }
}

// Acklam inverse-normal approx + 3 double Newton refinements
__device__ double ndtri_acklam(double p) {
    const double a0 = -3.969683028665376e+01, a1 = 2.209460984245205e+02,
                 a2 = -2.759285104469687e+02, a3 = 1.383577518672690e+02,
                 a4 = -3.066479806614716e+01, a5 = 2.506628277459239e+00;
    const double b0 = -5.447609879822406e+01, b1 = 1.615858368580409e+02,
                 b2 = -1.556989798598866e+02, b3 = 6.680131188771972e+01,
                 b4 = -1.328068155288572e+01;
    const double c0 = -7.784894002430293e-03, c1 = -3.223964580411365e-01,
                 c2 = -2.400758277161838e+00, c3 = -2.549732539343734e+00,
                 c4 =  4.374664141464968e+00, c5 =  2.938163982698783e+00;
    const double d0 = 7.784695709041462e-03, d1 = 3.224671290700398e-01,
                 d2 = 2.445134137142996e+00, d3 = 3.754408661907416e+00;
    const double plow = 0.02425;
    double x;
    if (p < plow) {
        double q = sqrt(-2.0 * log(p));
        x = (((((c0*q+c1)*q+c2)*q+c3)*q+c4)*q+c5) /
            ((((d0*q+d1)*q+d2)*q+d3)*q+1.0);
    } else if (p > 1.0 - plow) {
        double q = sqrt(-2.0 * log(1.0 - p));
        x = -(((((c0*q+c1)*q+c2)*q+c3)*q+c4)*q+c5) /
             ((((d0*q+d1)*q+d2)*q+d3)*q+1.0);
    } else {
        double q = p - 0.5, r = q * q;
        x = (((((a0*r+a1)*r+a2)*r+a3)*r+a4)*r+a5)*q /
            (((((b0*r+b1)*r+b2)*r+b3)*r+b4)*r+1.0);
    }
    #pragma unroll
    for (int it = 0; it < 3; ++it) {
        double cdf = 0.5 * erfc(-x * 0.70710678118654752440);
        double pdf = exp(-0.5 * x * x) * 0.39894228040143267794;
        x -= (cdf - p) / pdf;
    }
    return x;
}

__global__ void k_prep(const float* __restrict__ temp, float* ws) {
    int k = threadIdx.x;
    if (k == 0) {
        double sum = (double)ws[0];
        double sumsq = (double)ws[1];
        const double N = (double)NB * (double)NC;
        double var = (sumsq - sum * sum / N) / (N - 1.0);
        ws[3] = (float)(1.0 / (sqrt(var) * (double)temp[0]));
    }
    if (k < NS) {
        double p = ((double)k + 0.5) / (double)NS;
        float tkf = (float)ndtri_acklam(p);
        ws[8 + k]  = tkf;
        ws[24 + k] = log_ndtr_f(tkf);
    }
}

// Build the log_ndtr interpolation table in double precision.
__global__ __launch_bounds__(256) void k_table(float2* __restrict__ tab) {
    int i = blockIdx.x * blockDim.x + threadIdx.x;
    if (i >= NT) return;
    double x0 = (double)XLO + (double)i / 64.0;
    double x1 = x0 + 1.0 / 64.0;
    double v0 = log(0.5 * erfc(-x0 * 0.70710678118654752440));
    double v1 = log(0.5 * erfc(-x1 * 0.70710678118654752440));
    tab[i] = make_float2((float)v0, (float)(v1 - v0));
}

__global__ __launch_bounds__(256) void k_main(const float* __restrict__ logits,
                                              const int* __restrict__ labels,
                                              const float* __restrict__ ws,
                                              const float2* __restrict__ tab,
                                              float* __restrict__ acc) {
    __shared__ float2 lt[NT];
    __shared__ float red[4][NS];
    for (int i = threadIdx.x; i < NT; i += 256) lt[i] = tab[i];

    const float inv_s = ws[3];
    const float s64 = inv_s * INVH;
    float ok[NS], ck[NS];
    #pragma unroll
    for (int k = 0; k < NS; ++k) {
        ok[k] = ws[8 + k] * INVH;   // t_k / h
        ck[k] = ws[24 + k];
    }
    __syncthreads();

    const int wid = threadIdx.x >> 6, lane = threadIdx.x & 63;
    float blockSum = 0.0f;

    for (int r = 0; r < ROWS; ++r) {
        const int b = blockIdx.x * ROWS + r;
        const float* row = logits + (size_t)b * NC;
        const float tgt = row[labels[b]];
        float4 v = reinterpret_cast<const float4*>(row)[threadIdx.x];

        // u_base_j = (d_j - XLO)/h, with d_j = (tgt - l_j)*inv_s
        float ub[4];
        ub[0] = (tgt - v.x) * s64 + (-XLO * INVH);
        ub[1] = (tgt - v.y) * s64 + (-XLO * INVH);
        ub[2] = (tgt - v.z) * s64 + (-XLO * INVH);
        ub[3] = (tgt - v.w) * s64 + (-XLO * INVH);

        float a[NS];
        #pragma unroll
        for (int k = 0; k < NS; ++k) a[k] = 0.0f;

        #pragma unroll
        for (int j = 0; j < 4; ++j) {
            #pragma unroll
            for (int k = 0; k < NS; ++k) {
                float u = ub[j] + ok[k];
                u = fminf(fmaxf(u, 0.0f), (float)(NT - 2) + 0.999f);
                float fl = floorf(u);
                int idx = (int)fl;
                float fr = u - fl;
                float2 e = lt[idx];
                a[k] += fmaf(fr, e.y, e.x);
            }
        }

        #pragma unroll
        for (int k = 0; k < NS; ++k) {
            #pragma unroll
            for (int m = 32; m; m >>= 1) a[k] += __shfl_xor(a[k], m, 64);
        }

        if (lane == 0) {
            #pragma unroll
            for (int k = 0; k < NS; ++k) red[wid][k] = a[k];
        }
        __syncthreads();
        if (threadIdx.x < NS) {
            int k = threadIdx.x;
            float sk = red[0][k] + red[1][k] + red[2][k] + red[3][k];
            float p = __expf(sk - ck[k]);   // remove the j==y (d=0) term
            p += __shfl_xor(p, 8, 16);
            p += __shfl_xor(p, 4, 16);
            p += __shfl_xor(p, 2, 16);
            p += __shfl_xor(p, 1, 16);
            if (k == 0) blockSum += p * (1.0f / (float)NS);
        }
        __syncthreads();   // protect red[] reuse next row
    }
    if (threadIdx.x == 0) atomicAdd(acc, blockSum);
}

__global__ void k_final(const float* __restrict__ ws, float* __restrict__ out) {
    if (threadIdx.x == 0 && blockIdx.x == 0) {
        out[0] = 1.0f - ws[2] * (1.0f / (float)NB);
    }
}

extern "C" void kernel_launch(void* const* d_in, const int* in_sizes, int n_in,
                              void* d_out, int out_size, void* d_ws, size_t ws_size,
                              hipStream_t stream) {
    const float* logits = (const float*)d_in[0];
    const int*   labels = (const int*)d_in[1];
    const float* temp   = (const float*)d_in[2];
    float* ws  = (float*)d_ws;
    float2* tab = (float2*)(ws + 64);
    float* out = (float*)d_out;

    hipLaunchKernelGGL(k_init,   dim3(1),    dim3(64),  0, stream, ws);
    hipLaunchKernelGGL(k_reduce, dim3(1024), dim3(256), 0, stream,
                       (const float4*)logits, ws);
    hipLaunchKernelGGL(k_prep,   dim3(1),    dim3(64),  0, stream, temp, ws);
    hipLaunchKernelGGL(k_table,  dim3((NT + 255) / 256), dim3(256), 0, stream, tab);
    hipLaunchKernelGGL(k_main,   dim3(NB / ROWS), dim3(256), 0, stream,
                       logits, labels, ws, (const float2*)tab, &ws[2]);
    hipLaunchKernelGGL(k_final,  dim3(1),    dim3(1),   0, stream, ws, out);
}

// Round 4
// 87.436 us; speedup vs baseline: 6.4442x; 1.2658x over previous
//
#include <hip/hip_runtime.h>
#include <math.h>

#define NB 8192
#define NC 1024
#define NS 16
#define ROWS 4

// nearest-neighbor log_ndtr table: x in [-13, 6], h = 1/256
#define NT 4865
#define BOFF 3328.5f   // 13*256 + 0.5 (rounding fold)

// ws layout (floats):
// [0] sum, [1] sumsq, [2] prob accumulator, [3] inv_s
// [8..23]  t_k
// [64..]   table: NT floats

__device__ __forceinline__ float log_ndtr_f(float x) {
    float e = erfcf(-x * 0.70710678118654752f);
    if (e > 1e-37f) return __logf(0.5f * e);
    return -0.5f * x * x - 0.91893853320467274f - __logf(-x);
}

// k_table: builds the table AND zeroes the ws header (replaces k_init)
__global__ __launch_bounds__(256) void k_table(float* __restrict__ tab, float* ws) {
    int i = blockIdx.x * blockDim.x + threadIdx.x;
    if (i < 8) ws[i] = 0.0f;
    if (i >= NT) return;
    double x = -13.0 + (double)i / 256.0;
    tab[i] = (float)log(0.5 * erfc(-x * 0.70710678118654752440));
}

__global__ __launch_bounds__(256) void k_reduce(const float4* __restrict__ x, float* ws) {
    const int total = (NB * NC) / 4;
    int idx = blockIdx.x * blockDim.x + threadIdx.x;
    float s = 0.0f, ss = 0.0f;
    for (int i = idx; i < total; i += gridDim.x * blockDim.x) {
        float4 v = x[i];
        s  += v.x + v.y + v.z + v.w;
        ss += v.x * v.x + v.y * v.y + v.z * v.z + v.w * v.w;
    }
    #pragma unroll
    for (int m = 32; m; m >>= 1) {
        s  += __shfl_xor(s,  m, 64);
        ss += __shfl_xor(ss, m, 64);
    }
    __shared__ float ls[4], lss[4];
    int wid = threadIdx.x >> 6, lane = threadIdx.x & 63;
    if (lane == 0) { ls[wid] = s; lss[wid] = ss; }
    __syncthreads();
    if (threadIdx.x == 0) {
        atomicAdd(&ws[0], ls[0] + ls[1] + ls[2] + ls[3]);
        atomicAdd(&ws[1], lss[0] + lss[1] + lss[2] + lss[3]);
    }
}

// Acklam inverse-normal approx + 3 double Newton refinements
__device__ double ndtri_acklam(double p) {
    const double a0 = -3.969683028665376e+01, a1 = 2.209460984245205e+02,
                 a2 = -2.759285104469687e+02, a3 = 1.383577518672690e+02,
                 a4 = -3.066479806614716e+01, a5 = 2.506628277459239e+00;
    const double b0 = -5.447609879822406e+01, b1 = 1.615858368580409e+02,
                 b2 = -1.556989798598866e+02, b3 = 6.680131188771972e+01,
                 b4 = -1.328068155288572e+01;
    const double c0 = -7.784894002430293e-03, c1 = -3.223964580411365e-01,
                 c2 = -2.400758277161838e+00, c3 = -2.549732539343734e+00,
                 c4 =  4.374664141464968e+00, c5 =  2.938163982698783e+00;
    const double d0 = 7.784695709041462e-03, d1 = 3.224671290700398e-01,
                 d2 = 2.445134137142996e+00, d3 = 3.754408661907416e+00;
    const double plow = 0.02425;
    double x;
    if (p < plow) {
        double q = sqrt(-2.0 * log(p));
        x = (((((c0*q+c1)*q+c2)*q+c3)*q+c4)*q+c5) /
            ((((d0*q+d1)*q+d2)*q+d3)*q+1.0);
    } else if (p > 1.0 - plow) {
        double q = sqrt(-2.0 * log(1.0 - p));
        x = -(((((c0*q+c1)*q+c2)*q+c3)*q+c4)*q+c5) /
             ((((d0*q+d1)*q+d2)*q+d3)*q+1.0);
    } else {
        double q = p - 0.5, r = q * q;
        x = (((((a0*r+a1)*r+a2)*r+a3)*r+a4)*r+a5)*q /
            (((((b0*r+b1)*r+b2)*r+b3)*r+b4)*r+1.0);
    }
    #pragma unroll
    for (int it = 0; it < 3; ++it) {
        double cdf = 0.5 * erfc(-x * 0.70710678118654752440);
        double pdf = exp(-0.5 * x * x) * 0.39894228040143267794;
        x -= (cdf - p) / pdf;
    }
    return x;
}

__global__ void k_prep(const float* __restrict__ temp, float* ws) {
    int k = threadIdx.x;
    if (k == 0) {
        double sum = (double)ws[0];
        double sumsq = (double)ws[1];
        const double N = (double)NB * (double)NC;
        double var = (sumsq - sum * sum / N) / (N - 1.0);
        ws[3] = (float)(1.0 / (sqrt(var) * (double)temp[0]));
    }
    if (k < NS) {
        double p = ((double)k + 0.5) / (double)NS;
        ws[8 + k] = (float)ndtri_acklam(p);
    }
}

__global__ __launch_bounds__(256) void k_main(const float* __restrict__ logits,
                                              const int* __restrict__ labels,
                                              const float* __restrict__ ws,
                                              const float* __restrict__ tab,
                                              float* __restrict__ acc) {
    __shared__ float lt[NT];
    __shared__ float red[4][NS];
    for (int i = threadIdx.x; i < NT; i += 256) lt[i] = tab[i];

    const float s256 = ws[3] * 256.0f;
    const int l = threadIdx.x & 63, w = threadIdx.x >> 6;
    const int kg = l & 3, jg = l >> 2;   // lane owns k = kg*4+kk, columns jg*16.. of wave's quarter

    float ok4[4];
    #pragma unroll
    for (int kk = 0; kk < 4; ++kk)
        ok4[kk] = ws[8 + kg * 4 + kk] * 256.0f + BOFF;

    __syncthreads();

    // exact y-term correction: same lookup the y-column produces (d_y == 0)
    float ckt = 0.0f;
    if (threadIdx.x < NS) {
        float uk = ws[8 + threadIdx.x] * 256.0f + BOFF;
        uk = fminf(fmaxf(uk, 0.0f), (float)(NT - 1));
        ckt = lt[(int)uk];
    }

    const float4* __restrict__ lf4 = (const float4*)logits;
    float blockSum = 0.0f;

    for (int r = 0; r < ROWS; ++r) {
        const int b = blockIdx.x * ROWS + r;
        const float* row = logits + (size_t)b * NC;
        const float tgt = row[labels[b]];

        // lane loads its 16 columns: float4 indices base..base+3 of this row
        const int base = b * (NC / 4) + w * 64 + jg * 4;
        float4 v0 = lf4[base + 0];
        float4 v1 = lf4[base + 1];
        float4 v2 = lf4[base + 2];
        float4 v3 = lf4[base + 3];

        float ub[16];
        ub[0]  = (tgt - v0.x) * s256; ub[1]  = (tgt - v0.y) * s256;
        ub[2]  = (tgt - v0.z) * s256; ub[3]  = (tgt - v0.w) * s256;
        ub[4]  = (tgt - v1.x) * s256; ub[5]  = (tgt - v1.y) * s256;
        ub[6]  = (tgt - v1.z) * s256; ub[7]  = (tgt - v1.w) * s256;
        ub[8]  = (tgt - v2.x) * s256; ub[9]  = (tgt - v2.y) * s256;
        ub[10] = (tgt - v2.z) * s256; ub[11] = (tgt - v2.w) * s256;
        ub[12] = (tgt - v3.x) * s256; ub[13] = (tgt - v3.y) * s256;
        ub[14] = (tgt - v3.z) * s256; ub[15] = (tgt - v3.w) * s256;

        float a[4] = {0.0f, 0.0f, 0.0f, 0.0f};
        #pragma unroll
        for (int m = 0; m < 16; ++m) {
            #pragma unroll
            for (int kk = 0; kk < 4; ++kk) {
                float u = ub[m] + ok4[kk];
                u = fminf(fmaxf(u, 0.0f), (float)(NT - 1));
                a[kk] += lt[(int)u];
            }
        }

        // butterfly over the 16 j-groups (masks flip jg bits; kg invariant)
        #pragma unroll
        for (int kk = 0; kk < 4; ++kk) {
            a[kk] += __shfl_xor(a[kk], 4,  64);
            a[kk] += __shfl_xor(a[kk], 8,  64);
            a[kk] += __shfl_xor(a[kk], 16, 64);
            a[kk] += __shfl_xor(a[kk], 32, 64);
        }

        if (l < 4) {   // lane l holds totals for kg=l: k = l*4+kk
            #pragma unroll
            for (int kk = 0; kk < 4; ++kk) red[w][l * 4 + kk] = a[kk];
        }
        __syncthreads();
        if (threadIdx.x < NS) {
            int k = threadIdx.x;
            float sk = red[0][k] + red[1][k] + red[2][k] + red[3][k];
            float p = __expf(sk - ckt);
            p += __shfl_xor(p, 8, 16);
            p += __shfl_xor(p, 4, 16);
            p += __shfl_xor(p, 2, 16);
            p += __shfl_xor(p, 1, 16);
            if (k == 0) blockSum += p * (1.0f / (float)NS);
        }
        __syncthreads();
    }
    if (threadIdx.x == 0) atomicAdd(acc, blockSum);
}

__global__ void k_final(const float* __restrict__ ws, float* __restrict__ out) {
    if (threadIdx.x == 0 && blockIdx.x == 0) {
        out[0] = 1.0f - ws[2] * (1.0f / (float)NB);
    }
}

extern "C" void kernel_launch(void* const* d_in, const int* in_sizes, int n_in,
                              void* d_out, int out_size, void* d_ws, size_t ws_size,
                              hipStream_t stream) {
    const float* logits = (const float*)d_in[0];
    const int*   labels = (const int*)d_in[1];
    const float* temp   = (const float*)d_in[2];
    float* ws  = (float*)d_ws;
    float* tab = ws + 64;
    float* out = (float*)d_out;

    hipLaunchKernelGGL(k_table,  dim3((NT + 255) / 256), dim3(256), 0, stream, tab, ws);
    hipLaunchKernelGGL(k_reduce, dim3(1024), dim3(256), 0, stream,
                       (const float4*)logits, ws);
    hipLaunchKernelGGL(k_prep,   dim3(1),    dim3(64),  0, stream, temp, ws);
    hipLaunchKernelGGL(k_main,   dim3(NB / ROWS), dim3(256), 0, stream,
                       logits, labels, ws, (const float*)tab, &ws[2]);
    hipLaunchKernelGGL(k_final,  dim3(1),    dim3(1),   0, stream, ws, out);
}

// Round 5
// 75.126 us; speedup vs baseline: 7.5000x; 1.1638x over previous
//
#include <hip/hip_runtime.h>
#include <math.h>

#define NB 8192
#define NC 1024
#define NS 16

// log_ndtr nearest-neighbor table: x_i = -9.5 + i/128, entries 0..NTR-1 real
#define NT   2464
#define NTR  2461
#define C0   48          // skip row if count(l_j >= l_y) - 1 >= C0
#define BMAXF 1984.0f    // base-index clamp hi (so base+476 <= 2460)
#define UBIAS 978.5f     // 9.5*128 - 238 + 0.5 (fold: round + okint[0] bias)

// OFFK[k] = round(t_k*128) + 238, t_k = ndtri((k+0.5)/16) quantized to grid
constexpr int OFFK[16] = {0, 69, 109, 139, 164, 187, 208, 228,
                          248, 268, 289, 312, 337, 367, 407, 476};

// ws float layout:
// [0] prob acc   [1](int) finalize ticket
// [16..1039]   per-block partial sum (1024)
// [1040..2063] per-block partial sumsq (1024)
// [2064..10255] (int) per-row counts (8192)
// [10256..10256+NT) table

__global__ __launch_bounds__(256) void k_pre(const float* __restrict__ logits,
                                             const int* __restrict__ labels,
                                             float* __restrict__ ws) {
    const int bid = blockIdx.x;
    if (bid >= 1024) {
        // table build + header zeroing
        if (bid == 1024) {
            if (threadIdx.x == 0) ws[0] = 0.0f;
            if (threadIdx.x == 1) ((int*)ws)[1] = 0;
        }
        int i = (bid - 1024) * 256 + threadIdx.x;
        if (i < NT) {
            int ii = i < NTR ? i : (NTR - 1);
            double x = -9.5 + (double)ii * (1.0 / 128.0);
            ws[10256 + i] = (float)log(0.5 * erfc(-x * 0.70710678118654752440));
        }
        return;
    }
    const int w = threadIdx.x >> 6, l = threadIdx.x & 63;
    const float4* lf4 = (const float4*)logits;
    float s = 0.0f, ss = 0.0f;
    for (int rr = 0; rr < 2; ++rr) {
        const int row = bid * 8 + w * 2 + rr;
        const float tgt = logits[row * NC + labels[row]];
        int cnt = 0;
        #pragma unroll
        for (int i = 0; i < 4; ++i) {
            float4 v = lf4[row * (NC / 4) + l + 64 * i];
            s  += v.x + v.y + v.z + v.w;
            ss += v.x * v.x + v.y * v.y + v.z * v.z + v.w * v.w;
            cnt += (v.x >= tgt) + (v.y >= tgt) + (v.z >= tgt) + (v.w >= tgt);
        }
        #pragma unroll
        for (int m = 32; m; m >>= 1) cnt += __shfl_xor(cnt, m, 64);
        if (l == 0) ((int*)ws)[2064 + row] = cnt - 1;   // exclude self-compare
    }
    #pragma unroll
    for (int m = 32; m; m >>= 1) {
        s  += __shfl_xor(s,  m, 64);
        ss += __shfl_xor(ss, m, 64);
    }
    __shared__ float bs[4], bss[4];
    if (l == 0) { bs[w] = s; bss[w] = ss; }
    __syncthreads();
    if (threadIdx.x == 0) {
        ws[16 + bid]   = bs[0] + bs[1] + bs[2] + bs[3];
        ws[1040 + bid] = bss[0] + bss[1] + bss[2] + bss[3];
    }
}

__global__ __launch_bounds__(256) void k_main(const float* __restrict__ logits,
                                              const int* __restrict__ labels,
                                              const float* __restrict__ temp,
                                              float* __restrict__ ws,
                                              float* __restrict__ out) {
    const int bid = blockIdx.x, tid = threadIdx.x;
    const int* wsi = (const int*)ws;
    const int c0 = wsi[2064 + bid * 4 + 0], c1 = wsi[2064 + bid * 4 + 1],
              c2 = wsi[2064 + bid * 4 + 2], c3 = wsi[2064 + bid * 4 + 3];
    const bool anylive = (c0 < C0) | (c1 < C0) | (c2 < C0) | (c3 < C0);

    if (anylive) {
        __shared__ float lt[NT];
        __shared__ float rs[4], rss[4];
        __shared__ float shInv;
        // cooperative table load (L2-hot)
        float4* lt4 = (float4*)lt;
        const float4* gt4 = (const float4*)(ws + 10256);
        for (int i = tid; i < NT / 4; i += 256) lt4[i] = gt4[i];
        // inline inv_s from the 1024 partials
        float s  = ws[16 + tid] + ws[16 + 256 + tid] + ws[16 + 512 + tid] + ws[16 + 768 + tid];
        float ss = ws[1040 + tid] + ws[1040 + 256 + tid] + ws[1040 + 512 + tid] + ws[1040 + 768 + tid];
        #pragma unroll
        for (int m = 32; m; m >>= 1) {
            s  += __shfl_xor(s,  m, 64);
            ss += __shfl_xor(ss, m, 64);
        }
        const int w = tid >> 6, l = tid & 63;
        if (l == 0) { rs[w] = s; rss[w] = ss; }
        __syncthreads();
        if (tid == 0) {
            float S1 = rs[0] + rs[1] + rs[2] + rs[3];
            float S2 = rss[0] + rss[1] + rss[2] + rss[3];
            const float N = (float)NB * (float)NC;
            float var = (S2 - S1 * S1 / N) / (N - 1.0f);
            shInv = 128.0f / (sqrtf(var) * temp[0]);
        }
        __syncthreads();
        const float s128 = shInv;

        const int row = bid * 4 + w;
        const int myc = (w == 0) ? c0 : ((w == 1) ? c1 : ((w == 2) ? c2 : c3));
        if (myc < C0) {
            const float4* lf4 = (const float4*)logits;
            const float tgt = logits[row * NC + labels[row]];
            const float A = fmaf(tgt, s128, UBIAS);
            float a[16];
            #pragma unroll
            for (int k = 0; k < 16; ++k) a[k] = 0.0f;
            #pragma unroll
            for (int i = 0; i < 4; ++i) {
                float4 v = lf4[row * (NC / 4) + l + 64 * i];
                float vv[4] = {v.x, v.y, v.z, v.w};
                #pragma unroll
                for (int j = 0; j < 4; ++j) {
                    float u = fmaf(vv[j], -s128, A);
                    u = fminf(fmaxf(u, 0.0f), BMAXF);
                    int bi = (int)u;
                    #pragma unroll
                    for (int k = 0; k < 16; ++k) a[k] += lt[bi + OFFK[k]];
                }
            }
            #pragma unroll
            for (int k = 0; k < 16; ++k) {
                #pragma unroll
                for (int m = 32; m; m >>= 1) a[k] += __shfl_xor(a[k], m, 64);
            }
            // exact y-term cancellation: same float ops as the j==y column
            float uy = fmaf(tgt, -s128, A);
            uy = fminf(fmaxf(uy, 0.0f), BMAXF);
            int by = (int)uy;
            float prob = 0.0f;
            #pragma unroll
            for (int k = 0; k < 16; ++k) prob += __expf(a[k] - lt[by + OFFK[k]]);
            if (l == 0) atomicAdd(&ws[0], prob * (1.0f / 16.0f));
        }
        __syncthreads();
    }

    if (tid == 0) {
        __threadfence();
        int t = atomicAdd((int*)ws + 1, 1);
        if (t == (int)gridDim.x - 1) {
            float acc = atomicAdd(&ws[0], 0.0f);   // coherent read
            out[0] = 1.0f - acc * (1.0f / (float)NB);
        }
    }
}

extern "C" void kernel_launch(void* const* d_in, const int* in_sizes, int n_in,
                              void* d_out, int out_size, void* d_ws, size_t ws_size,
                              hipStream_t stream) {
    const float* logits = (const float*)d_in[0];
    const int*   labels = (const int*)d_in[1];
    const float* temp   = (const float*)d_in[2];
    float* ws  = (float*)d_ws;
    float* out = (float*)d_out;

    hipLaunchKernelGGL(k_pre,  dim3(1024 + (NT + 255) / 256), dim3(256), 0, stream,
                       logits, labels, ws);
    hipLaunchKernelGGL(k_main, dim3(NB / 4), dim3(256), 0, stream,
                       logits, labels, temp, ws, out);
}

// Round 6
// 25.611 us; speedup vs baseline: 22.0007x; 2.9334x over previous
//
#include <hip/hip_runtime.h>
#include <math.h>

#define NB 8192
#define NC 1024
#define NS 16

// log_ndtr nearest-neighbor table: x_i = -9.5 + i/128, entries 0..NTR-1 real
#define NT   2464
#define NTR  2461
#define C0   48          // skip row if count(l_j >= l_y) - 1 >= C0
#define BMAXF 1984.0f    // base-index clamp hi (so base+476 <= 2460)
#define UBIAS 978.5f     // 9.5*128 - 238 + 0.5 (fold: round + okint[0] bias)

// OFFK[k] = round(t_k*128) + 238, t_k = ndtri((k+0.5)/16) quantized to grid
constexpr int OFFK[16] = {0, 69, 109, 139, 164, 187, 208, 228,
                          248, 268, 289, 312, 337, 367, 407, 476};

// ws layout (float/int indices):
// [16..1039]    per-block partial sum (1024)
// [1040..2063]  per-block partial sumsq (1024)
// [2064..3087]  (int) per-region live count (1024 regions of 8 rows)
// [3088..11279] (int) per-region live row ids (1024*8)
// [11280..11407] per-k_main-block prob partials (128)
// [11408..11408+NT) table
#define PSUM  16
#define PSQ   1040
#define RCNT  2064
#define RLIST 3088
#define PART  11280
#define TAB   11408
#define NBLK_MAIN 128

__global__ __launch_bounds__(256) void k_pre(const float* __restrict__ logits,
                                             const int* __restrict__ labels,
                                             float* __restrict__ ws) {
    const int bid = blockIdx.x;
    if (bid >= 1024) {
        // table build
        int i = (bid - 1024) * 256 + threadIdx.x;
        if (i < NT) {
            int ii = i < NTR ? i : (NTR - 1);
            double x = -9.5 + (double)ii * (1.0 / 128.0);
            ws[TAB + i] = (float)log(0.5 * erfc(-x * 0.70710678118654752440));
        }
        return;
    }
    const int w = threadIdx.x >> 6, l = threadIdx.x & 63;
    const float4* lf4 = (const float4*)logits;
    __shared__ int flags[8];
    __shared__ float bs[4], bss[4];
    float s = 0.0f, ss = 0.0f;
    for (int rr = 0; rr < 2; ++rr) {
        const int row = bid * 8 + w * 2 + rr;
        const float tgt = logits[row * NC + labels[row]];
        int cnt = 0;
        #pragma unroll
        for (int i = 0; i < 4; ++i) {
            float4 v = lf4[row * (NC / 4) + l + 64 * i];
            s  += v.x + v.y + v.z + v.w;
            ss += v.x * v.x + v.y * v.y + v.z * v.z + v.w * v.w;
            cnt += (v.x >= tgt) + (v.y >= tgt) + (v.z >= tgt) + (v.w >= tgt);
        }
        #pragma unroll
        for (int m = 32; m; m >>= 1) cnt += __shfl_xor(cnt, m, 64);
        if (l == 0) flags[w * 2 + rr] = ((cnt - 1) < C0);   // cnt-1: exclude self
    }
    #pragma unroll
    for (int m = 32; m; m >>= 1) {
        s  += __shfl_xor(s,  m, 64);
        ss += __shfl_xor(ss, m, 64);
    }
    if (l == 0) { bs[w] = s; bss[w] = ss; }
    __syncthreads();
    if (threadIdx.x == 0) {
        ws[PSUM + bid] = bs[0] + bs[1] + bs[2] + bs[3];
        ws[PSQ + bid]  = bss[0] + bss[1] + bss[2] + bss[3];
        int* wsi = (int*)ws;
        int n = 0;
        #pragma unroll
        for (int i = 0; i < 8; ++i)
            if (flags[i]) wsi[RLIST + bid * 8 + (n++)] = bid * 8 + i;
        wsi[RCNT + bid] = n;
    }
}

__global__ __launch_bounds__(256) void k_main(const float* __restrict__ logits,
                                              const int* __restrict__ labels,
                                              const float* __restrict__ temp,
                                              float* __restrict__ ws) {
    const int bid = blockIdx.x, tid = threadIdx.x;
    const int* wsi = (const int*)ws;
    __shared__ int rows[64];
    __shared__ int nrows;
    __shared__ float lt[NT];
    __shared__ float rs[4], rss[4];
    __shared__ float shInv;
    __shared__ float wprob[4];

    if (tid == 0) {
        int n = 0;
        for (int r = 0; r < 8; ++r) {
            int reg = bid * 8 + r;
            int c = wsi[RCNT + reg];
            for (int i = 0; i < c; ++i) rows[n++] = wsi[RLIST + reg * 8 + i];
        }
        nrows = n;
    }
    __syncthreads();
    if (nrows == 0) {
        if (tid == 0) ws[PART + bid] = 0.0f;
        return;
    }

    // cooperative table load
    float4* lt4 = (float4*)lt;
    const float4* gt4 = (const float4*)(ws + TAB);
    for (int i = tid; i < NT / 4; i += 256) lt4[i] = gt4[i];

    // inline inv_s from the 1024 partials
    float s  = ws[PSUM + tid] + ws[PSUM + 256 + tid] + ws[PSUM + 512 + tid] + ws[PSUM + 768 + tid];
    float ss = ws[PSQ + tid]  + ws[PSQ + 256 + tid]  + ws[PSQ + 512 + tid]  + ws[PSQ + 768 + tid];
    #pragma unroll
    for (int m = 32; m; m >>= 1) {
        s  += __shfl_xor(s,  m, 64);
        ss += __shfl_xor(ss, m, 64);
    }
    const int w = tid >> 6, l = tid & 63;
    if (l == 0) { rs[w] = s; rss[w] = ss; }
    __syncthreads();
    if (tid == 0) {
        float S1 = rs[0] + rs[1] + rs[2] + rs[3];
        float S2 = rss[0] + rss[1] + rss[2] + rss[3];
        const float N = (float)NB * (float)NC;
        float var = (S2 - S1 * S1 / N) / (N - 1.0f);
        shInv = 128.0f / (sqrtf(var) * temp[0]);
    }
    __syncthreads();
    const float s128 = shInv;
    const int nr = nrows;

    const float4* lf4 = (const float4*)logits;
    float waveProb = 0.0f;

    for (int i = w; i < nr; i += 4) {
        const int row = rows[i];
        const float tgt = logits[row * NC + labels[row]];
        const float A = fmaf(tgt, s128, UBIAS);
        float a[16];
        #pragma unroll
        for (int k = 0; k < 16; ++k) a[k] = 0.0f;
        #pragma unroll
        for (int ii = 0; ii < 4; ++ii) {
            float4 v = lf4[row * (NC / 4) + l + 64 * ii];
            float vv[4] = {v.x, v.y, v.z, v.w};
            #pragma unroll
            for (int j = 0; j < 4; ++j) {
                float u = fmaf(vv[j], -s128, A);
                u = fminf(fmaxf(u, 0.0f), BMAXF);
                int bi = (int)u;
                #pragma unroll
                for (int k = 0; k < 16; ++k) a[k] += lt[bi + OFFK[k]];
            }
        }
        #pragma unroll
        for (int k = 0; k < 16; ++k) {
            #pragma unroll
            for (int m = 32; m; m >>= 1) a[k] += __shfl_xor(a[k], m, 64);
        }
        // exact y-term cancellation: same float ops as the j==y column
        float uy = fmaf(tgt, -s128, A);
        uy = fminf(fmaxf(uy, 0.0f), BMAXF);
        int by = (int)uy;
        float prob = 0.0f;
        #pragma unroll
        for (int k = 0; k < 16; ++k) prob += __expf(a[k] - lt[by + OFFK[k]]);
        waveProb += prob * (1.0f / 16.0f);
    }

    if (l == 0) wprob[w] = waveProb;
    __syncthreads();
    if (tid == 0) ws[PART + bid] = wprob[0] + wprob[1] + wprob[2] + wprob[3];
}

__global__ __launch_bounds__(128) void k_final(const float* __restrict__ ws,
                                               float* __restrict__ out) {
    const int tid = threadIdx.x;
    float p = ws[PART + tid];
    #pragma unroll
    for (int m = 32; m; m >>= 1) p += __shfl_xor(p, m, 64);
    __shared__ float t[2];
    if ((tid & 63) == 0) t[tid >> 6] = p;
    __syncthreads();
    if (tid == 0) out[0] = 1.0f - (t[0] + t[1]) * (1.0f / (float)NB);
}

extern "C" void kernel_launch(void* const* d_in, const int* in_sizes, int n_in,
                              void* d_out, int out_size, void* d_ws, size_t ws_size,
                              hipStream_t stream) {
    const float* logits = (const float*)d_in[0];
    const int*   labels = (const int*)d_in[1];
    const float* temp   = (const float*)d_in[2];
    float* ws  = (float*)d_ws;
    float* out = (float*)d_out;

    hipLaunchKernelGGL(k_pre,   dim3(1024 + (NT + 255) / 256), dim3(256), 0, stream,
                       logits, labels, ws);
    hipLaunchKernelGGL(k_main,  dim3(NBLK_MAIN), dim3(256), 0, stream,
                       logits, labels, temp, ws);
    hipLaunchKernelGGL(k_final, dim3(1), dim3(128), 0, stream, ws, out);
}

// Round 7
// 21.087 us; speedup vs baseline: 26.7197x; 1.2145x over previous
//
#include <hip/hip_runtime.h>
#include <math.h>

#define NB 8192
#define NC 1024
#define NS 16

// log_ndtr nearest-neighbor table: x_i = -9.5 + i/128, entries 0..NTR-1 real
#define NT   2464
#define NTR  2461
#define C0   48          // skip row if count(l_j >= l_y) - 1 >= C0
#define BMAXF 1984.0f    // base-index clamp hi (so base+476 <= 2460)
#define UBIAS 978.5f     // 9.5*128 - 238 + 0.5 (fold: round + okint[0] bias)

// OFFK[k] = round(t_k*128) + 238, t_k = ndtri((k+0.5)/16) quantized to grid
constexpr int OFFK[16] = {0, 69, 109, 139, 164, 187, 208, 228,
                          248, 268, 289, 312, 337, 367, 407, 476};

// ws layout (float/int indices):
// [16..1039]    per-block partial sum (1024)
// [1040..2063]  per-block partial sumsq (1024)
// [2064..3087]  (int) per-region live count (1024 regions of 8 rows)
// [3088..11279] (int) per-region live row ids (1024*8)
// [11280..11407] per-k_main-block prob partials (128)
// [11408..11408+NT) table
#define PSUM  16
#define PSQ   1040
#define RCNT  2064
#define RLIST 3088
#define PART  11280
#define TAB   11408
#define NBLK_MAIN 128

__global__ __launch_bounds__(256) void k_pre(const float* __restrict__ logits,
                                             const int* __restrict__ labels,
                                             float* __restrict__ ws) {
    const int bid = blockIdx.x;
    if (bid >= 1024) {
        // table build
        int i = (bid - 1024) * 256 + threadIdx.x;
        if (i < NT) {
            int ii = i < NTR ? i : (NTR - 1);
            double x = -9.5 + (double)ii * (1.0 / 128.0);
            ws[TAB + i] = (float)log(0.5 * erfc(-x * 0.70710678118654752440));
        }
        return;
    }
    const int w = threadIdx.x >> 6, l = threadIdx.x & 63;
    const float4* lf4 = (const float4*)logits;
    __shared__ int flags[8];
    __shared__ float bs[4], bss[4];
    float s = 0.0f, ss = 0.0f;
    for (int rr = 0; rr < 2; ++rr) {
        const int row = bid * 8 + w * 2 + rr;
        const float tgt = logits[row * NC + labels[row]];
        int cnt = 0;
        #pragma unroll
        for (int i = 0; i < 4; ++i) {
            float4 v = lf4[row * (NC / 4) + l + 64 * i];
            s  += v.x + v.y + v.z + v.w;
            ss += v.x * v.x + v.y * v.y + v.z * v.z + v.w * v.w;
            cnt += (v.x >= tgt) + (v.y >= tgt) + (v.z >= tgt) + (v.w >= tgt);
        }
        #pragma unroll
        for (int m = 32; m; m >>= 1) cnt += __shfl_xor(cnt, m, 64);
        if (l == 0) flags[w * 2 + rr] = ((cnt - 1) < C0);   // cnt-1: exclude self
    }
    #pragma unroll
    for (int m = 32; m; m >>= 1) {
        s  += __shfl_xor(s,  m, 64);
        ss += __shfl_xor(ss, m, 64);
    }
    if (l == 0) { bs[w] = s; bss[w] = ss; }
    __syncthreads();
    if (threadIdx.x == 0) {
        ws[PSUM + bid] = bs[0] + bs[1] + bs[2] + bs[3];
        ws[PSQ + bid]  = bss[0] + bss[1] + bss[2] + bss[3];
        int* wsi = (int*)ws;
        int n = 0;
        #pragma unroll
        for (int i = 0; i < 8; ++i)
            if (flags[i]) wsi[RLIST + bid * 8 + (n++)] = bid * 8 + i;
        wsi[RCNT + bid] = n;
    }
}

__global__ __launch_bounds__(256) void k_main(const float* __restrict__ logits,
                                              const int* __restrict__ labels,
                                              const float* __restrict__ temp,
                                              float* __restrict__ ws) {
    const int bid = blockIdx.x, tid = threadIdx.x;
    const int* wsi = (const int*)ws;
    const int w = tid >> 6, l = tid & 63;

    __shared__ float lt[NT];
    __shared__ int   P[1024];
    __shared__ int   wtot[4];
    __shared__ float rs[4], rss[4];
    __shared__ float shInv;
    __shared__ float wprob[4];

    // cooperative table load (L2-hot)
    float4* lt4 = (float4*)lt;
    const float4* gt4 = (const float4*)(ws + TAB);
    for (int i = tid; i < NT / 4; i += 256) lt4[i] = gt4[i];

    // ---- global prefix sum of region counts (redundant per block, L2-hot) ----
    int c4[4];
    const int b4 = tid * 4;
    #pragma unroll
    for (int j = 0; j < 4; ++j) c4[j] = wsi[RCNT + b4 + j];
    int s4 = c4[0] + c4[1] + c4[2] + c4[3];
    // inclusive wave scan of s4
    int v = s4;
    #pragma unroll
    for (int off = 1; off < 64; off <<= 1) {
        int u = __shfl_up(v, off, 64);
        if (l >= off) v += u;
    }
    if (l == 63) wtot[w] = v;

    // ---- inv_s from the 1024 partials (runs while scan LDS settles) ----
    float s  = ws[PSUM + tid] + ws[PSUM + 256 + tid] + ws[PSUM + 512 + tid] + ws[PSUM + 768 + tid];
    float ss = ws[PSQ + tid]  + ws[PSQ + 256 + tid]  + ws[PSQ + 512 + tid]  + ws[PSQ + 768 + tid];
    #pragma unroll
    for (int m = 32; m; m >>= 1) {
        s  += __shfl_xor(s,  m, 64);
        ss += __shfl_xor(ss, m, 64);
    }
    if (l == 0) { rs[w] = s; rss[w] = ss; }
    __syncthreads();

    int wbase = 0;
    #pragma unroll
    for (int ww = 0; ww < 4; ++ww) if (ww < w) wbase += wtot[ww];
    int ex = wbase + v - s4;   // exclusive prefix for this thread's 4 regions
    P[b4 + 0] = ex;
    P[b4 + 1] = ex + c4[0];
    P[b4 + 2] = ex + c4[0] + c4[1];
    P[b4 + 3] = ex + c4[0] + c4[1] + c4[2];
    const int Ntot = wtot[0] + wtot[1] + wtot[2] + wtot[3];

    if (tid == 0) {
        float S1 = rs[0] + rs[1] + rs[2] + rs[3];
        float S2 = rss[0] + rss[1] + rss[2] + rss[3];
        const float N = (float)NB * (float)NC;
        float var = (S2 - S1 * S1 / N) / (N - 1.0f);
        shInv = 128.0f / (sqrtf(var) * temp[0]);
    }
    __syncthreads();
    const float s128 = shInv;

    const float4* lf4 = (const float4*)logits;
    float waveProb = 0.0f;
    const int gwave = bid * 4 + w;   // 512 waves total

    for (int i = gwave; i < Ntot; i += NBLK_MAIN * 4) {
        // binary search: last region with P[reg] <= i
        int lo = 0, hi = 1023;
        while (lo < hi) {
            int mid = (lo + hi + 1) >> 1;
            if (P[mid] <= i) lo = mid; else hi = mid - 1;
        }
        const int row = wsi[RLIST + lo * 8 + (i - P[lo])];

        const float tgt = logits[row * NC + labels[row]];
        const float A = fmaf(tgt, s128, UBIAS);
        float a[16];
        #pragma unroll
        for (int k = 0; k < 16; ++k) a[k] = 0.0f;
        #pragma unroll
        for (int ii = 0; ii < 4; ++ii) {
            float4 vv4 = lf4[row * (NC / 4) + l + 64 * ii];
            float vv[4] = {vv4.x, vv4.y, vv4.z, vv4.w};
            #pragma unroll
            for (int j = 0; j < 4; ++j) {
                float u = fmaf(vv[j], -s128, A);
                u = fminf(fmaxf(u, 0.0f), BMAXF);
                int bi = (int)u;
                #pragma unroll
                for (int k = 0; k < 16; ++k) a[k] += lt[bi + OFFK[k]];
            }
        }
        #pragma unroll
        for (int k = 0; k < 16; ++k) {
            #pragma unroll
            for (int m = 32; m; m >>= 1) a[k] += __shfl_xor(a[k], m, 64);
        }
        // exact y-term cancellation: same float ops as the j==y column
        float uy = fmaf(tgt, -s128, A);
        uy = fminf(fmaxf(uy, 0.0f), BMAXF);
        int by = (int)uy;
        float prob = 0.0f;
        #pragma unroll
        for (int k = 0; k < 16; ++k) prob += __expf(a[k] - lt[by + OFFK[k]]);
        waveProb += prob * (1.0f / 16.0f);
    }

    if (l == 0) wprob[w] = waveProb;
    __syncthreads();
    if (tid == 0) ws[PART + bid] = wprob[0] + wprob[1] + wprob[2] + wprob[3];
}

__global__ __launch_bounds__(128) void k_final(const float* __restrict__ ws,
                                               float* __restrict__ out) {
    const int tid = threadIdx.x;
    float p = ws[PART + tid];
    #pragma unroll
    for (int m = 32; m; m >>= 1) p += __shfl_xor(p, m, 64);
    __shared__ float t[2];
    if ((tid & 63) == 0) t[tid >> 6] = p;
    __syncthreads();
    if (tid == 0) out[0] = 1.0f - (t[0] + t[1]) * (1.0f / (float)NB);
}

extern "C" void kernel_launch(void* const* d_in, const int* in_sizes, int n_in,
                              void* d_out, int out_size, void* d_ws, size_t ws_size,
                              hipStream_t stream) {
    const float* logits = (const float*)d_in[0];
    const int*   labels = (const int*)d_in[1];
    const float* temp   = (const float*)d_in[2];
    float* ws  = (float*)d_ws;
    float* out = (float*)d_out;

    hipLaunchKernelGGL(k_pre,   dim3(1024 + (NT + 255) / 256), dim3(256), 0, stream,
                       logits, labels, ws);
    hipLaunchKernelGGL(k_main,  dim3(NBLK_MAIN), dim3(256), 0, stream,
                       logits, labels, temp, ws);
    hipLaunchKernelGGL(k_final, dim3(1), dim3(128), 0, stream, ws, out);
}